// Round 13
// baseline (432.142 us; speedup 1.0000x reference)
//
#include <hip/hip_runtime.h>
#include <hip/hip_bf16.h>
#include <stdint.h>

#define NHEAD 12
#define SEQ   2048
#define NB    8
#define MTOK  (NB*SEQ)        // 16384
#define DIMC  768
#define QKVN  (3*DIMC)        // 2304

typedef __attribute__((ext_vector_type(8))) short bf16x8;
typedef __attribute__((ext_vector_type(4))) float f32x4;
typedef __attribute__((ext_vector_type(16))) float f32x16;
typedef __attribute__((ext_vector_type(4))) unsigned short u16x4;
typedef __attribute__((ext_vector_type(4))) unsigned int u32x4;

typedef const __attribute__((address_space(1))) char glb_char;
typedef __attribute__((address_space(3))) char lds_char;

__device__ __forceinline__ unsigned short f2bf(float f) {
  union { float f; unsigned u; } v; v.f = f;
  return (unsigned short)((v.u + 0x7FFFu + ((v.u >> 16) & 1u)) >> 16);
}

__device__ __forceinline__ void gload_lds16(const void* g, void* l) {
  __builtin_amdgcn_global_load_lds((glb_char*)g, (lds_char*)l, 16, 0, 0);
}

__device__ __forceinline__ unsigned cvtpk_bf16(float lo, float hi) {
  unsigned d;
  asm("v_cvt_pk_bf16_f32 %0, %1, %2" : "=v"(d) : "v"(lo), "v"(hi));
  return d;
}

// q pre-scale folds softmax scale AND log2(e) so attn uses raw exp2 (v_exp_f32)
#define QSCALE 0.18033688011112042f   // 0.125 * log2(e)
#define MASKBIAS -30000.0f

// ---------------- fp32 -> bf16 convert ----------------
__global__ void __launch_bounds__(256, 8)
cvt_bf16_kernel(const float* __restrict__ in,
                unsigned short* __restrict__ out, int n4) {
  int idx = blockIdx.x * blockDim.x + threadIdx.x;
  int stride = gridDim.x * blockDim.x;
  for (int i = idx; i < n4; i += stride) {
    float4 v = ((const float4*)in)[i];
    u16x4 o;
    o.x = f2bf(v.x); o.y = f2bf(v.y); o.z = f2bf(v.z); o.w = f2bf(v.w);
    ((u16x4*)out)[i] = o;
  }
}

// ---------------- mask scan: compacted positions, inverse map, bias ----------------
__global__ void __launch_bounds__(256, 4)
maskscan_kernel(const int* __restrict__ mask, int* __restrict__ posmap,
                int* __restrict__ srcidx, float* __restrict__ mbias_c,
                int* __restrict__ nvalid) {
  __shared__ int sums[256];
  __shared__ int btot;
  const int b = blockIdx.x, t = threadIdx.x;
  const int* m = mask + b * SEQ;
  int loc[8];
  int s = 0;
  #pragma unroll
  for (int i = 0; i < 8; i++) { loc[i] = (m[t * 8 + i] != 0) ? 1 : 0; s += loc[i]; }
  sums[t] = s;
  __syncthreads();
  for (int off = 1; off < 256; off <<= 1) {
    int v = (t >= off) ? sums[t - off] : 0;
    __syncthreads();
    sums[t] += v;
    __syncthreads();
  }
  int excl = sums[t] - s;           // exclusive prefix of this thread's chunk
  if (t == 255) btot = sums[255];
  __syncthreads();
  const int nv = btot;
  #pragma unroll
  for (int i = 0; i < 8; i++) {
    posmap[b * SEQ + t * 8 + i] = loc[i] ? excl : -1;
    if (loc[i]) srcidx[b * SEQ + excl] = t * 8 + i;
    excl += loc[i];
  }
  for (int j = t; j < SEQ; j += 256) {
    mbias_c[b * SEQ + j] = (j < nv) ? 0.0f : MASKBIAS;
    if (j >= nv) srcidx[b * SEQ + j] = 0;
  }
  if (t == 0) nvalid[b] = nv;
}

// ---------------- zero the pad tail of compacted K / V^T ----------------
__global__ void __launch_bounds__(256, 8)
zerotail_kernel(unsigned short* __restrict__ kc, unsigned short* __restrict__ vc,
                const int* __restrict__ nvalid) {
  const int bh = blockIdx.x, t = threadIdx.x;
  const int b = bh / NHEAD;
  const int nv = nvalid[b];
  const int pad = (nv + 63) & ~63;
  const int nz = pad - nv;
  if (nz == 0) return;
  unsigned short* kcb = kc + (size_t)bh * SEQ * 64;
  unsigned short* vcb = vc + (size_t)bh * 64 * SEQ;
  for (int i = t; i < nz * 64; i += 256) {
    int r = i >> 6, d = i & 63;
    kcb[(nv + r) * 64 + d] = 0;
  }
  for (int i = t; i < 64 * nz; i += 256) {
    int d = i / nz, c = i - d * nz;
    vcb[(size_t)d * SEQ + nv + c] = 0;
  }
}

// ---------------- fp32 [R][C] -> bf16 [C][R] transpose ----------------
__global__ void __launch_bounds__(256, 8)
transpose_cvt_kernel(const float* __restrict__ in,
                     unsigned short* __restrict__ out,
                     int R, int C) {
  __shared__ float tile[32][33];
  int c0 = blockIdx.x * 32, r0 = blockIdx.y * 32;
  int tx = threadIdx.x & 31, ty = threadIdx.x >> 5;  // 256 thr: ty 0..7
  #pragma unroll
  for (int i = 0; i < 32; i += 8)
    tile[ty + i][tx] = in[(size_t)(r0 + ty + i) * C + c0 + tx];
  __syncthreads();
  #pragma unroll
  for (int i = 0; i < 32; i += 8)
    out[(size_t)(c0 + ty + i) * R + r0 + tx] = f2bf(tile[tx][ty + i]);
}

// ---------------- Q GEMM: 2-phase dbuf, 5 blocks/CU (TLP latency hiding) ----------------
__global__ void __launch_bounds__(256, 5)
q_gemm_kernel(const unsigned short* __restrict__ xb,
              const unsigned short* __restrict__ wT,
              unsigned short* __restrict__ qo) {
  __shared__ short lA[2][128 * 32];
  __shared__ short lB[2][128 * 32];
  const int t = threadIdx.x;
  const int lane = t & 63, w = t >> 6;
  const int m0 = blockIdx.x * 128;
  const int n0 = blockIdx.y * 128;
  const int wr = (w >> 1) * 64, wc = (w & 1) * 64;
  const int l15 = lane & 15, lg = lane >> 4;
  const int sr = t >> 2;
  const int sc = t & 3;

  auto STAGE = [&](int k0, int bsel) {
    #pragma unroll
    for (int i = 0; i < 2; i++) {
      int row = i * 64 + sr;
      int cb = (sc ^ ((row >> 1) & 3)) * 8;
      gload_lds16(xb + (size_t)(m0 + row) * DIMC + k0 + cb,
                  (char*)lA + bsel * 8192 + i * 4096 + w * 1024);
      gload_lds16(wT + (size_t)(n0 + row) * DIMC + k0 + cb,
                  (char*)lB + bsel * 8192 + i * 4096 + w * 1024);
    }
  };

  f32x4 acc[4][4] = {};

  STAGE(0, 0);
  asm volatile("s_waitcnt vmcnt(0)" ::: "memory");
  __builtin_amdgcn_s_barrier();

  for (int k0 = 0; k0 < DIMC; k0 += 32) {
    const int bsel = (k0 >> 5) & 1;
    if (k0 + 32 < DIMC) STAGE(k0 + 32, bsel ^ 1);
    const short* A = &lA[bsel][0];
    const short* B = &lB[bsel][0];

    bf16x8 af[4], bfr[4];
    #pragma unroll
    for (int mi = 0; mi < 4; mi++) {
      int m = wr + mi * 16 + l15;
      af[mi] = *(const bf16x8*)&A[m * 32 + ((lg ^ ((m >> 1) & 3)) << 3)];
    }
    #pragma unroll
    for (int nj = 0; nj < 4; nj++) {
      int n = wc + nj * 16 + l15;
      bfr[nj] = *(const bf16x8*)&B[n * 32 + ((lg ^ ((n >> 1) & 3)) << 3)];
    }
    __builtin_amdgcn_s_setprio(1);
    #pragma unroll
    for (int mi = 0; mi < 4; mi++)
      #pragma unroll
      for (int nj = 0; nj < 4; nj++)
        acc[mi][nj] = __builtin_amdgcn_mfma_f32_16x16x32_bf16(af[mi], bfr[nj], acc[mi][nj], 0, 0, 0);
    __builtin_amdgcn_s_setprio(0);

    if (k0 + 32 < DIMC) {
      asm volatile("s_waitcnt vmcnt(0)" ::: "memory");
      __builtin_amdgcn_s_barrier();
    }
  }

  #pragma unroll
  for (int mi = 0; mi < 4; mi++) {
    int tok0 = m0 + wr + mi * 16 + 4 * lg;
    int bb = tok0 >> 11;
    int nn0 = tok0 & 2047;
    #pragma unroll
    for (int nj = 0; nj < 4; nj++) {
      int col = n0 + wc + nj * 16 + l15;    // < 768
      int hh = col >> 6, dd = col & 63;
      size_t base = (((size_t)(bb * NHEAD + hh)) * SEQ + nn0) * 64 + dd;
      #pragma unroll
      for (int r = 0; r < 4; r++)
        qo[base + (size_t)r * 64] = f2bf(acc[mi][nj][r] * QSCALE);
    }
  }
}

// ---------------- KV GEMM over COMPACTED rows, 2-phase dbuf, 5 blocks/CU ----------------
__global__ void __launch_bounds__(256, 5)
kv_gemm_kernel(const unsigned short* __restrict__ xb,
               const unsigned short* __restrict__ wT,
               unsigned short* __restrict__ ko,
               unsigned short* __restrict__ vto,
               const int* __restrict__ srcidx,
               const int* __restrict__ nvalid) {
  const int b = blockIdx.z;
  const int m0 = blockIdx.x * 128;
  if (m0 >= ((nvalid[b] + 127) & ~127)) return;
  __shared__ short lA[2][128 * 32];
  __shared__ short lB[2][128 * 32];
  const int t = threadIdx.x;
  const int lane = t & 63, w = t >> 6;
  const int n0 = blockIdx.y * 128;
  const int wr = (w >> 1) * 64, wc = (w & 1) * 64;
  const int l15 = lane & 15, lg = lane >> 4;
  const int sr = t >> 2;
  const int sc = t & 3;

  const int srow0 = srcidx[b * SEQ + m0 + sr];
  const int srow1 = srcidx[b * SEQ + m0 + 64 + sr];
  const unsigned short* xbb = xb + (size_t)b * SEQ * DIMC;
  const unsigned short* wTkv = wT + (size_t)DIMC * DIMC;  // rows [768, 2304)

  auto STAGE = [&](int k0, int bsel) {
    int cb = (sc ^ ((sr >> 1) & 3)) * 8;
    gload_lds16(xbb + (size_t)srow0 * DIMC + k0 + cb,
                (char*)lA + bsel * 8192 + w * 1024);
    gload_lds16(xbb + (size_t)srow1 * DIMC + k0 + cb,
                (char*)lA + bsel * 8192 + 4096 + w * 1024);
    #pragma unroll
    for (int i = 0; i < 2; i++) {
      int row = i * 64 + sr;
      int cb2 = (sc ^ ((row >> 1) & 3)) * 8;
      gload_lds16(wTkv + (size_t)(n0 + row) * DIMC + k0 + cb2,
                  (char*)lB + bsel * 8192 + i * 4096 + w * 1024);
    }
  };

  f32x4 acc[4][4] = {};

  STAGE(0, 0);
  asm volatile("s_waitcnt vmcnt(0)" ::: "memory");
  __builtin_amdgcn_s_barrier();

  for (int k0 = 0; k0 < DIMC; k0 += 32) {
    const int bsel = (k0 >> 5) & 1;
    if (k0 + 32 < DIMC) STAGE(k0 + 32, bsel ^ 1);
    const short* A = &lA[bsel][0];
    const short* B = &lB[bsel][0];

    bf16x8 af[4], bfr[4];
    #pragma unroll
    for (int mi = 0; mi < 4; mi++) {
      int m = wr + mi * 16 + l15;
      af[mi] = *(const bf16x8*)&A[m * 32 + ((lg ^ ((m >> 1) & 3)) << 3)];
    }
    #pragma unroll
    for (int nj = 0; nj < 4; nj++) {
      int n = wc + nj * 16 + l15;
      bfr[nj] = *(const bf16x8*)&B[n * 32 + ((lg ^ ((n >> 1) & 3)) << 3)];
    }
    __builtin_amdgcn_s_setprio(1);
    #pragma unroll
    for (int mi = 0; mi < 4; mi++)
      #pragma unroll
      for (int nj = 0; nj < 4; nj++)
        acc[mi][nj] = __builtin_amdgcn_mfma_f32_16x16x32_bf16(af[mi], bfr[nj], acc[mi][nj], 0, 0, 0);
    __builtin_amdgcn_s_setprio(0);

    if (k0 + 32 < DIMC) {
      asm volatile("s_waitcnt vmcnt(0)" ::: "memory");
      __builtin_amdgcn_s_barrier();
    }
  }

  #pragma unroll
  for (int mi = 0; mi < 4; mi++) {
    int pos0 = m0 + wr + mi * 16 + 4 * lg;
    #pragma unroll
    for (int nj = 0; nj < 4; nj++) {
      int col = n0 + wc + nj * 16 + l15;     // [0,1536)
      int ch = (col >= DIMC) ? col - DIMC : col;
      int hh = ch >> 6, dd = ch & 63;
      size_t hb = (size_t)(b * NHEAD + hh);
      if (col < DIMC) {
        size_t base = (hb * SEQ + pos0) * 64 + dd;
        #pragma unroll
        for (int r = 0; r < 4; r++)
          ko[base + (size_t)r * 64] = f2bf(acc[mi][nj][r]);
      } else {
        size_t base = (hb * 64 + dd) * SEQ + pos0;
        u16x4 pk;
        pk.x = f2bf(acc[mi][nj][0]); pk.y = f2bf(acc[mi][nj][1]);
        pk.z = f2bf(acc[mi][nj][2]); pk.w = f2bf(acc[mi][nj][3]);
        *(u16x4*)(vto + base) = pk;
      }
    }
  }
}

// ---------------- flash attention over COMPACTED keys (r11 verified) ----------------
__global__ void __launch_bounds__(256, 4)
attn_kernel(const unsigned short* __restrict__ qbuf,
            const unsigned short* __restrict__ kbuf,
            const unsigned short* __restrict__ vtbuf,
            const float* __restrict__ mbias_c,
            const int* __restrict__ nvalid,
            unsigned short* __restrict__ ao) {
  __shared__ short lKV[2][8192];   // [buf][ K: 8 chunks*1024B | V: 8 chunks*1024B ]
  __shared__ float lmask[2][64];   // bias double-buffer
  const int t = threadIdx.x, lane = t & 63, w = t >> 6;
  const int l31 = lane & 31, hi = lane >> 5;
  const int bid = blockIdx.x;
  const int qt = bid / 96;
  const int bh = bid - qt * 96;
  const int b = bh / NHEAD, h = bh - b * NHEAD;
  const int q0 = qt * 128 + w * 32;
  const unsigned short* qb = qbuf + (size_t)bh * SEQ * 64;
  const unsigned short* kb = kbuf + (size_t)bh * SEQ * 64;
  const unsigned short* vb = vtbuf + (size_t)bh * 64 * SEQ;
  const float* mb = mbias_c + b * SEQ;
  const int ntiles = (nvalid[b] + 63) >> 6;

  auto STAGE = [&](int tile, int bsel) {
    int kv0 = tile * 64;
    #pragma unroll
    for (int i = 0; i < 2; i++) {
      int c = i * 4 + w;
      gload_lds16(kb + (size_t)(kv0 + lane) * 64 + c * 8,
                  (char*)lKV + bsel * 16384 + c * 1024);
      gload_lds16(vb + (size_t)lane * SEQ + kv0 + c * 8,
                  (char*)lKV + bsel * 16384 + 8192 + c * 1024);
    }
    if (w == 0)
      __builtin_amdgcn_global_load_lds((glb_char*)(mb + tile * 64 + lane),
                                       (lds_char*)&lmask[bsel][0], 4, 0, 0);
  };

  // Q as B-operand: col=q=l31, k=d=dblk*16+hi*8+j
  bf16x8 qf[4];
  #pragma unroll
  for (int dblk = 0; dblk < 4; dblk++)
    qf[dblk] = *(const bf16x8*)(qb + (size_t)(q0 + l31) * 64 + dblk * 16 + hi * 8);

  f32x16 O[2] = {};         // O[dt]: rows=q(reg), cols=d=dt*32+l31
  float ls[4] = {0.f, 0.f, 0.f, 0.f};

  STAGE(0, 0);
  __syncthreads();

  for (int it = 0; it < ntiles; ++it) {
    const int bsel = it & 1;
    const short* Kb = &lKV[bsel][0];
    const short* Vb = &lKV[bsel][4096];
    if (it + 1 < ntiles) STAGE(it + 1, bsel ^ 1);

    #pragma unroll
    for (int kb2 = 0; kb2 < 2; kb2++) {
      // bias -> C-init (kv_local = (r&3)+8*(r>>2)+4*hi), broadcast LDS reads
      f32x4 mb4[4];
      #pragma unroll
      for (int g = 0; g < 4; g++)
        mb4[g] = *(const f32x4*)&lmask[bsel][kb2 * 32 + g * 8 + hi * 4];
      f32x16 S;
      #pragma unroll
      for (int r = 0; r < 16; r++) S[r] = mb4[r >> 2][r & 3];

      // ---- S^T = K . Q^T : contiguous reads, immediate offsets ----
      __builtin_amdgcn_s_setprio(1);
      #pragma unroll
      for (int dblk = 0; dblk < 4; dblk++) {
        bf16x8 kf = *(const bf16x8*)&Kb[(dblk * 2 + hi) * 512 + (kb2 * 32 + l31) * 8];
        S = __builtin_amdgcn_mfma_f32_32x32x16_bf16(kf, qf[dblk], S, 0, 0, 0);
      }
      __builtin_amdgcn_s_setprio(0);

      // ---- p = exp2(s); per-lane row-sums (kv is lane-local) ----
      float p[16];
      #pragma unroll
      for (int r = 0; r < 16; r++) p[r] = __builtin_amdgcn_exp2f(S[r]);
      #pragma unroll
      for (int r = 0; r < 16; r++) ls[r & 3] += p[r];

      // ---- PV A-frags (cvt_pk + permlane32_swap), consumed immediately ----
      #pragma unroll
      for (int half = 0; half < 2; half++) {
        unsigned a0 = cvtpk_bf16(p[half * 8 + 0], p[half * 8 + 1]);
        unsigned a1 = cvtpk_bf16(p[half * 8 + 2], p[half * 8 + 3]);
        unsigned a2 = cvtpk_bf16(p[half * 8 + 4], p[half * 8 + 5]);
        unsigned a3 = cvtpk_bf16(p[half * 8 + 6], p[half * 8 + 7]);
        asm("v_permlane32_swap_b32 %0, %1" : "+v"(a0), "+v"(a2));
        asm("v_permlane32_swap_b32 %0, %1" : "+v"(a1), "+v"(a3));
        union { u32x4 u; bf16x8 f; } cv;
        cv.u = (u32x4){a0, a1, a2, a3};
        // ---- PV: O[dt] += P . V (contiguous V reads) ----
        __builtin_amdgcn_s_setprio(1);
        #pragma unroll
        for (int dt = 0; dt < 2; dt++) {
          bf16x8 vf = *(const bf16x8*)&Vb[(kb2 * 4 + half * 2 + hi) * 512 + (dt * 32 + l31) * 8];
          O[dt] = __builtin_amdgcn_mfma_f32_32x32x16_bf16(cv.f, vf, O[dt], 0, 0, 0);
        }
        __builtin_amdgcn_s_setprio(0);
      }
    }

    if (it + 1 < ntiles) {
      asm volatile("s_waitcnt vmcnt(0)" ::: "memory");  // next tile + bias landed
      __builtin_amdgcn_s_barrier();
    }
  }

  // row-sum broadcast via LDS aliased onto dead K/V buffer 0
  __syncthreads();
  float* lrs = (float*)&lKV[0][0];   // per-wave 128B, disjoint
  float tot = (ls[0] + ls[1]) + (ls[2] + ls[3]);
  tot += __shfl_xor(tot, 32);
  lrs[w * 32 + l31] = tot;

  float inv[16];
  #pragma unroll
  for (int r = 0; r < 16; r++)
    inv[r] = 1.0f / lrs[w * 32 + (r & 3) + 8 * (r >> 2) + 4 * hi];

  #pragma unroll
  for (int dt = 0; dt < 2; dt++) {
    #pragma unroll
    for (int r = 0; r < 16; r++) {
      int qrow = q0 + (r & 3) + 8 * (r >> 2) + 4 * hi;
      size_t base = ((size_t)(b * SEQ + qrow)) * DIMC + h * 64 + dt * 32 + l31;
      ao[base] = __bfloat16_as_ushort(__float2bfloat16(O[dt][r] * inv[r]));
    }
  }
}

// ---------------- proj GEMM, 2-phase dbuf, 5 blocks/CU ----------------
__global__ void __launch_bounds__(256, 5)
proj_gemm_kernel(const unsigned short* __restrict__ ab,
                 const unsigned short* __restrict__ wT,
                 const float* __restrict__ bias,
                 float* __restrict__ out) {
  __shared__ short lA[2][128 * 32];
  __shared__ short lB[2][128 * 32];
  const int t = threadIdx.x;
  const int lane = t & 63, w = t >> 6;
  const int m0 = blockIdx.x * 128;
  const int n0 = blockIdx.y * 128;
  const int wr = (w >> 1) * 64, wc = (w & 1) * 64;
  const int l15 = lane & 15, lg = lane >> 4;
  const int sr = t >> 2;
  const int sc = t & 3;

  auto STAGE = [&](int k0, int bsel) {
    #pragma unroll
    for (int i = 0; i < 2; i++) {
      int row = i * 64 + sr;
      int cb = (sc ^ ((row >> 1) & 3)) * 8;
      gload_lds16(ab + (size_t)(m0 + row) * DIMC + k0 + cb,
                  (char*)lA + bsel * 8192 + i * 4096 + w * 1024);
      gload_lds16(wT + (size_t)(n0 + row) * DIMC + k0 + cb,
                  (char*)lB + bsel * 8192 + i * 4096 + w * 1024);
    }
  };

  f32x4 acc[4][4] = {};

  STAGE(0, 0);
  asm volatile("s_waitcnt vmcnt(0)" ::: "memory");
  __builtin_amdgcn_s_barrier();

  for (int k0 = 0; k0 < DIMC; k0 += 32) {
    const int bsel = (k0 >> 5) & 1;
    if (k0 + 32 < DIMC) STAGE(k0 + 32, bsel ^ 1);
    const short* A = &lA[bsel][0];
    const short* B = &lB[bsel][0];

    bf16x8 af[4], bfr[4];
    #pragma unroll
    for (int mi = 0; mi < 4; mi++) {
      int m = wr + mi * 16 + l15;
      af[mi] = *(const bf16x8*)&A[m * 32 + ((lg ^ ((m >> 1) & 3)) << 3)];
    }
    #pragma unroll
    for (int nj = 0; nj < 4; nj++) {
      int n = wc + nj * 16 + l15;
      bfr[nj] = *(const bf16x8*)&B[n * 32 + ((lg ^ ((n >> 1) & 3)) << 3)];
    }
    __builtin_amdgcn_s_setprio(1);
    #pragma unroll
    for (int mi = 0; mi < 4; mi++)
      #pragma unroll
      for (int nj = 0; nj < 4; nj++)
        acc[mi][nj] = __builtin_amdgcn_mfma_f32_16x16x32_bf16(af[mi], bfr[nj], acc[mi][nj], 0, 0, 0);
    __builtin_amdgcn_s_setprio(0);

    if (k0 + 32 < DIMC) {
      asm volatile("s_waitcnt vmcnt(0)" ::: "memory");
      __builtin_amdgcn_s_barrier();
    }
  }

  #pragma unroll
  for (int mi = 0; mi < 4; mi++) {
    int row0 = m0 + wr + mi * 16 + 4 * lg;
    #pragma unroll
    for (int nj = 0; nj < 4; nj++) {
      int col = n0 + wc + nj * 16 + l15;
      float bv = bias[col];
      #pragma unroll
      for (int r = 0; r < 4; r++)
        out[(size_t)(row0 + r) * DIMC + col] = acc[mi][nj][r] + bv;
    }
  }
}

extern "C" void kernel_launch(void* const* d_in, const int* in_sizes, int n_in,
                              void* d_out, int out_size, void* d_ws, size_t ws_size,
                              hipStream_t stream) {
  const float* x      = (const float*)d_in[0];
  const int*   mask   = (const int*)d_in[1];
  const float* w_qkv  = (const float*)d_in[2];
  const float* w_proj = (const float*)d_in[3];
  const float* b_proj = (const float*)d_in[4];
  float* out = (float*)d_out;

  unsigned short* ws = (unsigned short*)d_ws;
  unsigned short* xb     = ws;                                 // [16384][768]
  unsigned short* wqkvT  = xb    + (size_t)MTOK * DIMC;        // [2304][768]
  unsigned short* wprojT = wqkvT + (size_t)QKVN * DIMC;        // [768][768]
  unsigned short* qbuf   = wprojT + (size_t)DIMC * DIMC;       // [B,H,N,D]
  unsigned short* kbuf   = qbuf  + (size_t)MTOK * DIMC;        // [B,H,pos,D] compacted
  unsigned short* vtbuf  = kbuf  + (size_t)MTOK * DIMC;        // [B,H,D,pos] compacted
  float*          mbias_c = (float*)(vtbuf + (size_t)MTOK * DIMC); // [B][N]
  int*            posmap  = (int*)(mbias_c + MTOK);            // [B*N]
  int*            nvalid  = posmap + MTOK;                     // [8]
  int*            srcidx  = nvalid + 8;                        // [B*N]
  unsigned short* aob    = xb;   // alias: xb dead after kv_gemm

  cvt_bf16_kernel<<<2048, 256, 0, stream>>>(x, xb, MTOK * DIMC / 4);
  maskscan_kernel<<<NB, 256, 0, stream>>>(mask, posmap, srcidx, mbias_c, nvalid);
  transpose_cvt_kernel<<<dim3(QKVN / 32, DIMC / 32), 256, 0, stream>>>(w_qkv, wqkvT, DIMC, QKVN);
  transpose_cvt_kernel<<<dim3(DIMC / 32, DIMC / 32), 256, 0, stream>>>(w_proj, wprojT, DIMC, DIMC);
  q_gemm_kernel<<<dim3(128, 6), 256, 0, stream>>>(xb, wqkvT, qbuf);
  kv_gemm_kernel<<<dim3(16, 12, NB), 256, 0, stream>>>(xb, wqkvT, kbuf, vtbuf, srcidx, nvalid);
  zerotail_kernel<<<NB * NHEAD, 256, 0, stream>>>(kbuf, vtbuf, nvalid);
  attn_kernel<<<1536, 256, 0, stream>>>(qbuf, kbuf, vtbuf, mbias_c, nvalid, aob);
  proj_gemm_kernel<<<dim3(128, 6), 256, 0, stream>>>(aob, wprojT, b_proj, out);
}

// Round 14
// 199.983 us; speedup vs baseline: 2.1609x; 2.1609x over previous
//
#include <hip/hip_runtime.h>
#include <hip/hip_bf16.h>
#include <stdint.h>

#define NHEAD 12
#define SEQ   2048
#define NB    8
#define MTOK  (NB*SEQ)        // 16384
#define DIMC  768
#define QKVN  (3*DIMC)        // 2304

typedef __attribute__((ext_vector_type(8))) short bf16x8;
typedef __attribute__((ext_vector_type(4))) float f32x4;
typedef __attribute__((ext_vector_type(16))) float f32x16;
typedef __attribute__((ext_vector_type(4))) unsigned short u16x4;
typedef __attribute__((ext_vector_type(4))) unsigned int u32x4;

typedef const __attribute__((address_space(1))) char glb_char;
typedef __attribute__((address_space(3))) char lds_char;

__device__ __forceinline__ unsigned short f2bf(float f) {
  union { float f; unsigned u; } v; v.f = f;
  return (unsigned short)((v.u + 0x7FFFu + ((v.u >> 16) & 1u)) >> 16);
}

__device__ __forceinline__ void gload_lds16(const void* g, void* l) {
  __builtin_amdgcn_global_load_lds((glb_char*)g, (lds_char*)l, 16, 0, 0);
}

__device__ __forceinline__ unsigned cvtpk_bf16(float lo, float hi) {
  unsigned d;
  asm("v_cvt_pk_bf16_f32 %0, %1, %2" : "=v"(d) : "v"(lo), "v"(hi));
  return d;
}

// q pre-scale folds softmax scale AND log2(e) so attn uses raw exp2 (v_exp_f32)
#define QSCALE 0.18033688011112042f   // 0.125 * log2(e)
#define MASKBIAS -30000.0f

// ---------------- fp32 -> bf16 convert ----------------
__global__ void __launch_bounds__(256, 8)
cvt_bf16_kernel(const float* __restrict__ in,
                unsigned short* __restrict__ out, int n4) {
  int idx = blockIdx.x * blockDim.x + threadIdx.x;
  int stride = gridDim.x * blockDim.x;
  for (int i = idx; i < n4; i += stride) {
    float4 v = ((const float4*)in)[i];
    u16x4 o;
    o.x = f2bf(v.x); o.y = f2bf(v.y); o.z = f2bf(v.z); o.w = f2bf(v.w);
    ((u16x4*)out)[i] = o;
  }
}

// ---------------- mask scan: compacted positions, inverse map, bias ----------------
__global__ void __launch_bounds__(256, 4)
maskscan_kernel(const int* __restrict__ mask, int* __restrict__ posmap,
                int* __restrict__ srcidx, float* __restrict__ mbias_c,
                int* __restrict__ nvalid) {
  __shared__ int sums[256];
  __shared__ int btot;
  const int b = blockIdx.x, t = threadIdx.x;
  const int* m = mask + b * SEQ;
  int loc[8];
  int s = 0;
  #pragma unroll
  for (int i = 0; i < 8; i++) { loc[i] = (m[t * 8 + i] != 0) ? 1 : 0; s += loc[i]; }
  sums[t] = s;
  __syncthreads();
  for (int off = 1; off < 256; off <<= 1) {
    int v = (t >= off) ? sums[t - off] : 0;
    __syncthreads();
    sums[t] += v;
    __syncthreads();
  }
  int excl = sums[t] - s;           // exclusive prefix of this thread's chunk
  if (t == 255) btot = sums[255];
  __syncthreads();
  const int nv = btot;
  #pragma unroll
  for (int i = 0; i < 8; i++) {
    posmap[b * SEQ + t * 8 + i] = loc[i] ? excl : -1;
    if (loc[i]) srcidx[b * SEQ + excl] = t * 8 + i;
    excl += loc[i];
  }
  for (int j = t; j < SEQ; j += 256) {
    mbias_c[b * SEQ + j] = (j < nv) ? 0.0f : MASKBIAS;
    if (j >= nv) srcidx[b * SEQ + j] = 0;
  }
  if (t == 0) nvalid[b] = nv;
}

// ---------------- zero the pad tail of compacted K / V^T ----------------
__global__ void __launch_bounds__(256, 8)
zerotail_kernel(unsigned short* __restrict__ kc, unsigned short* __restrict__ vc,
                const int* __restrict__ nvalid) {
  const int bh = blockIdx.x, t = threadIdx.x;
  const int b = bh / NHEAD;
  const int nv = nvalid[b];
  const int pad = (nv + 63) & ~63;
  const int nz = pad - nv;
  if (nz == 0) return;
  unsigned short* kcb = kc + (size_t)bh * SEQ * 64;
  unsigned short* vcb = vc + (size_t)bh * 64 * SEQ;
  for (int i = t; i < nz * 64; i += 256) {
    int r = i >> 6, d = i & 63;
    kcb[(nv + r) * 64 + d] = 0;
  }
  for (int i = t; i < 64 * nz; i += 256) {
    int d = i / nz, c = i - d * nz;
    vcb[(size_t)d * SEQ + nv + c] = 0;
  }
}

// ---------------- fp32 [R][C] -> bf16 [C][R] transpose, both weights fused ----------------
// z=0: w_qkv (R=DIMC, C=QKVN) -> wqkvT ; z=1: w_proj (R=DIMC, C=DIMC) -> wprojT
__global__ void __launch_bounds__(256, 8)
transpose_cvt2_kernel(const float* __restrict__ in0, unsigned short* __restrict__ out0,
                      const float* __restrict__ in1, unsigned short* __restrict__ out1) {
  __shared__ float tile[32][33];
  const int z = blockIdx.z;
  const float* in = z ? in1 : in0;
  unsigned short* out = z ? out1 : out0;
  const int C = z ? DIMC : QKVN;
  const int R = DIMC;
  int c0 = blockIdx.x * 32, r0 = blockIdx.y * 32;
  if (c0 >= C) return;
  int tx = threadIdx.x & 31, ty = threadIdx.x >> 5;  // 256 thr: ty 0..7
  #pragma unroll
  for (int i = 0; i < 32; i += 8)
    tile[ty + i][tx] = in[(size_t)(r0 + ty + i) * C + c0 + tx];
  __syncthreads();
  #pragma unroll
  for (int i = 0; i < 32; i += 8)
    out[(size_t)(c0 + ty + i) * R + r0 + tx] = f2bf(tile[tx][ty + i]);
}

// ---------------- Q GEMM: [16384x768] @ wT-rows[0,768), 3-buf counted-vmcnt ----------------
__global__ void __launch_bounds__(256, 3)
q_gemm_kernel(const unsigned short* __restrict__ xb,
              const unsigned short* __restrict__ wT,
              unsigned short* __restrict__ qo) {
  __shared__ short lA[3][128 * 32];
  __shared__ short lB[3][128 * 32];
  const int t = threadIdx.x;
  const int lane = t & 63, w = t >> 6;
  const int m0 = blockIdx.x * 128;
  const int n0 = blockIdx.y * 128;
  const int wr = (w >> 1) * 64, wc = (w & 1) * 64;
  const int l15 = lane & 15, lg = lane >> 4;
  const int sr = t >> 2;
  const int sc = t & 3;

  auto STAGE = [&](int k0, int bsel) {
    #pragma unroll
    for (int i = 0; i < 2; i++) {
      int row = i * 64 + sr;
      int cb = (sc ^ ((row >> 1) & 3)) * 8;
      gload_lds16(xb + (size_t)(m0 + row) * DIMC + k0 + cb,
                  (char*)lA + bsel * 8192 + i * 4096 + w * 1024);
      gload_lds16(wT + (size_t)(n0 + row) * DIMC + k0 + cb,
                  (char*)lB + bsel * 8192 + i * 4096 + w * 1024);
    }
  };

  f32x4 acc[4][4] = {};
  const int NT = DIMC / 32;   // 24

  STAGE(0, 0);
  STAGE(32, 1);

  int cur = 0;
  for (int kt = 0; kt < NT; ++kt) {
    if (kt < NT - 1) asm volatile("s_waitcnt vmcnt(4)" ::: "memory");
    else             asm volatile("s_waitcnt vmcnt(0)" ::: "memory");
    __builtin_amdgcn_s_barrier();
    if (kt + 2 < NT) {
      int nb = cur + 2; if (nb >= 3) nb -= 3;
      STAGE((kt + 2) * 32, nb);
    }
    const short* A = &lA[cur][0];
    const short* B = &lB[cur][0];

    bf16x8 af[4], bfr[4];
    #pragma unroll
    for (int mi = 0; mi < 4; mi++) {
      int m = wr + mi * 16 + l15;
      af[mi] = *(const bf16x8*)&A[m * 32 + ((lg ^ ((m >> 1) & 3)) << 3)];
    }
    #pragma unroll
    for (int nj = 0; nj < 4; nj++) {
      int n = wc + nj * 16 + l15;
      bfr[nj] = *(const bf16x8*)&B[n * 32 + ((lg ^ ((n >> 1) & 3)) << 3)];
    }
    __builtin_amdgcn_s_setprio(1);
    #pragma unroll
    for (int mi = 0; mi < 4; mi++)
      #pragma unroll
      for (int nj = 0; nj < 4; nj++)
        acc[mi][nj] = __builtin_amdgcn_mfma_f32_16x16x32_bf16(af[mi], bfr[nj], acc[mi][nj], 0, 0, 0);
    __builtin_amdgcn_s_setprio(0);

    cur = (cur == 2) ? 0 : cur + 1;
  }

  #pragma unroll
  for (int mi = 0; mi < 4; mi++) {
    int tok0 = m0 + wr + mi * 16 + 4 * lg;
    int bb = tok0 >> 11;
    int nn0 = tok0 & 2047;
    #pragma unroll
    for (int nj = 0; nj < 4; nj++) {
      int col = n0 + wc + nj * 16 + l15;    // < 768
      int hh = col >> 6, dd = col & 63;
      size_t base = (((size_t)(bb * NHEAD + hh)) * SEQ + nn0) * 64 + dd;
      #pragma unroll
      for (int r = 0; r < 4; r++)
        qo[base + (size_t)r * 64] = f2bf(acc[mi][nj][r] * QSCALE);
    }
  }
}

// ---------------- KV GEMM over COMPACTED rows (gather-in-STAGE) ----------------
__global__ void __launch_bounds__(256, 3)
kv_gemm_kernel(const unsigned short* __restrict__ xb,
               const unsigned short* __restrict__ wT,
               unsigned short* __restrict__ ko,
               unsigned short* __restrict__ vto,
               const int* __restrict__ srcidx,
               const int* __restrict__ nvalid) {
  const int b = blockIdx.z;
  const int m0 = blockIdx.x * 128;
  if (m0 >= ((nvalid[b] + 127) & ~127)) return;
  __shared__ short lA[3][128 * 32];
  __shared__ short lB[3][128 * 32];
  const int t = threadIdx.x;
  const int lane = t & 63, w = t >> 6;
  const int n0 = blockIdx.y * 128;
  const int wr = (w >> 1) * 64, wc = (w & 1) * 64;
  const int l15 = lane & 15, lg = lane >> 4;
  const int sr = t >> 2;
  const int sc = t & 3;

  const int srow0 = srcidx[b * SEQ + m0 + sr];
  const int srow1 = srcidx[b * SEQ + m0 + 64 + sr];
  const unsigned short* xbb = xb + (size_t)b * SEQ * DIMC;
  const unsigned short* wTkv = wT + (size_t)DIMC * DIMC;  // rows [768, 2304)

  auto STAGE = [&](int k0, int bsel) {
    int cb = (sc ^ ((sr >> 1) & 3)) * 8;
    gload_lds16(xbb + (size_t)srow0 * DIMC + k0 + cb,
                (char*)lA + bsel * 8192 + w * 1024);
    gload_lds16(xbb + (size_t)srow1 * DIMC + k0 + cb,
                (char*)lA + bsel * 8192 + 4096 + w * 1024);
    #pragma unroll
    for (int i = 0; i < 2; i++) {
      int row = i * 64 + sr;
      int cb2 = (sc ^ ((row >> 1) & 3)) * 8;
      gload_lds16(wTkv + (size_t)(n0 + row) * DIMC + k0 + cb2,
                  (char*)lB + bsel * 8192 + i * 4096 + w * 1024);
    }
  };

  f32x4 acc[4][4] = {};
  const int NT = DIMC / 32;   // 24

  STAGE(0, 0);
  STAGE(32, 1);

  int cur = 0;
  for (int kt = 0; kt < NT; ++kt) {
    if (kt < NT - 1) asm volatile("s_waitcnt vmcnt(4)" ::: "memory");
    else             asm volatile("s_waitcnt vmcnt(0)" ::: "memory");
    __builtin_amdgcn_s_barrier();
    if (kt + 2 < NT) {
      int nb = cur + 2; if (nb >= 3) nb -= 3;
      STAGE((kt + 2) * 32, nb);
    }
    const short* A = &lA[cur][0];
    const short* B = &lB[cur][0];

    bf16x8 af[4], bfr[4];
    #pragma unroll
    for (int mi = 0; mi < 4; mi++) {
      int m = wr + mi * 16 + l15;
      af[mi] = *(const bf16x8*)&A[m * 32 + ((lg ^ ((m >> 1) & 3)) << 3)];
    }
    #pragma unroll
    for (int nj = 0; nj < 4; nj++) {
      int n = wc + nj * 16 + l15;
      bfr[nj] = *(const bf16x8*)&B[n * 32 + ((lg ^ ((n >> 1) & 3)) << 3)];
    }
    __builtin_amdgcn_s_setprio(1);
    #pragma unroll
    for (int mi = 0; mi < 4; mi++)
      #pragma unroll
      for (int nj = 0; nj < 4; nj++)
        acc[mi][nj] = __builtin_amdgcn_mfma_f32_16x16x32_bf16(af[mi], bfr[nj], acc[mi][nj], 0, 0, 0);
    __builtin_amdgcn_s_setprio(0);

    cur = (cur == 2) ? 0 : cur + 1;
  }

  #pragma unroll
  for (int mi = 0; mi < 4; mi++) {
    int pos0 = m0 + wr + mi * 16 + 4 * lg;
    #pragma unroll
    for (int nj = 0; nj < 4; nj++) {
      int col = n0 + wc + nj * 16 + l15;     // [0,1536)
      int ch = (col >= DIMC) ? col - DIMC : col;
      int hh = ch >> 6, dd = ch & 63;
      size_t hb = (size_t)(b * NHEAD + hh);
      if (col < DIMC) {
        size_t base = (hb * SEQ + pos0) * 64 + dd;
        #pragma unroll
        for (int r = 0; r < 4; r++)
          ko[base + (size_t)r * 64] = f2bf(acc[mi][nj][r]);
      } else {
        size_t base = (hb * 64 + dd) * SEQ + pos0;
        u16x4 pk;
        pk.x = f2bf(acc[mi][nj][0]); pk.y = f2bf(acc[mi][nj][1]);
        pk.z = f2bf(acc[mi][nj][2]); pk.w = f2bf(acc[mi][nj][3]);
        *(u16x4*)(vto + base) = pk;
      }
    }
  }
}

// ---------------- flash attention over COMPACTED keys (r11 verified) ----------------
__global__ void __launch_bounds__(256, 4)
attn_kernel(const unsigned short* __restrict__ qbuf,
            const unsigned short* __restrict__ kbuf,
            const unsigned short* __restrict__ vtbuf,
            const float* __restrict__ mbias_c,
            const int* __restrict__ nvalid,
            unsigned short* __restrict__ ao) {
  __shared__ short lKV[2][8192];   // [buf][ K: 8 chunks*1024B | V: 8 chunks*1024B ]
  __shared__ float lmask[2][64];   // bias double-buffer
  const int t = threadIdx.x, lane = t & 63, w = t >> 6;
  const int l31 = lane & 31, hi = lane >> 5;
  const int bid = blockIdx.x;
  const int qt = bid / 96;
  const int bh = bid - qt * 96;
  const int b = bh / NHEAD, h = bh - b * NHEAD;
  const int q0 = qt * 128 + w * 32;
  const unsigned short* qb = qbuf + (size_t)bh * SEQ * 64;
  const unsigned short* kb = kbuf + (size_t)bh * SEQ * 64;
  const unsigned short* vb = vtbuf + (size_t)bh * 64 * SEQ;
  const float* mb = mbias_c + b * SEQ;
  const int ntiles = (nvalid[b] + 63) >> 6;

  auto STAGE = [&](int tile, int bsel) {
    int kv0 = tile * 64;
    #pragma unroll
    for (int i = 0; i < 2; i++) {
      int c = i * 4 + w;
      gload_lds16(kb + (size_t)(kv0 + lane) * 64 + c * 8,
                  (char*)lKV + bsel * 16384 + c * 1024);
      gload_lds16(vb + (size_t)lane * SEQ + kv0 + c * 8,
                  (char*)lKV + bsel * 16384 + 8192 + c * 1024);
    }
    if (w == 0)
      __builtin_amdgcn_global_load_lds((glb_char*)(mb + tile * 64 + lane),
                                       (lds_char*)&lmask[bsel][0], 4, 0, 0);
  };

  // Q as B-operand: col=q=l31, k=d=dblk*16+hi*8+j
  bf16x8 qf[4];
  #pragma unroll
  for (int dblk = 0; dblk < 4; dblk++)
    qf[dblk] = *(const bf16x8*)(qb + (size_t)(q0 + l31) * 64 + dblk * 16 + hi * 8);

  f32x16 O[2] = {};         // O[dt]: rows=q(reg), cols=d=dt*32+l31
  float ls[4] = {0.f, 0.f, 0.f, 0.f};

  STAGE(0, 0);
  __syncthreads();

  for (int it = 0; it < ntiles; ++it) {
    const int bsel = it & 1;
    const short* Kb = &lKV[bsel][0];
    const short* Vb = &lKV[bsel][4096];
    if (it + 1 < ntiles) STAGE(it + 1, bsel ^ 1);

    #pragma unroll
    for (int kb2 = 0; kb2 < 2; kb2++) {
      // bias -> C-init (kv_local = (r&3)+8*(r>>2)+4*hi), broadcast LDS reads
      f32x4 mb4[4];
      #pragma unroll
      for (int g = 0; g < 4; g++)
        mb4[g] = *(const f32x4*)&lmask[bsel][kb2 * 32 + g * 8 + hi * 4];
      f32x16 S;
      #pragma unroll
      for (int r = 0; r < 16; r++) S[r] = mb4[r >> 2][r & 3];

      // ---- S^T = K . Q^T : contiguous reads, immediate offsets ----
      __builtin_amdgcn_s_setprio(1);
      #pragma unroll
      for (int dblk = 0; dblk < 4; dblk++) {
        bf16x8 kf = *(const bf16x8*)&Kb[(dblk * 2 + hi) * 512 + (kb2 * 32 + l31) * 8];
        S = __builtin_amdgcn_mfma_f32_32x32x16_bf16(kf, qf[dblk], S, 0, 0, 0);
      }
      __builtin_amdgcn_s_setprio(0);

      // ---- p = exp2(s); per-lane row-sums (kv is lane-local) ----
      float p[16];
      #pragma unroll
      for (int r = 0; r < 16; r++) p[r] = __builtin_amdgcn_exp2f(S[r]);
      #pragma unroll
      for (int r = 0; r < 16; r++) ls[r & 3] += p[r];

      // ---- PV A-frags (cvt_pk + permlane32_swap), consumed immediately ----
      #pragma unroll
      for (int half = 0; half < 2; half++) {
        unsigned a0 = cvtpk_bf16(p[half * 8 + 0], p[half * 8 + 1]);
        unsigned a1 = cvtpk_bf16(p[half * 8 + 2], p[half * 8 + 3]);
        unsigned a2 = cvtpk_bf16(p[half * 8 + 4], p[half * 8 + 5]);
        unsigned a3 = cvtpk_bf16(p[half * 8 + 6], p[half * 8 + 7]);
        asm("v_permlane32_swap_b32 %0, %1" : "+v"(a0), "+v"(a2));
        asm("v_permlane32_swap_b32 %0, %1" : "+v"(a1), "+v"(a3));
        union { u32x4 u; bf16x8 f; } cv;
        cv.u = (u32x4){a0, a1, a2, a3};
        // ---- PV: O[dt] += P . V (contiguous V reads) ----
        __builtin_amdgcn_s_setprio(1);
        #pragma unroll
        for (int dt = 0; dt < 2; dt++) {
          bf16x8 vf = *(const bf16x8*)&Vb[(kb2 * 4 + half * 2 + hi) * 512 + (dt * 32 + l31) * 8];
          O[dt] = __builtin_amdgcn_mfma_f32_32x32x16_bf16(cv.f, vf, O[dt], 0, 0, 0);
        }
        __builtin_amdgcn_s_setprio(0);
      }
    }

    if (it + 1 < ntiles) {
      asm volatile("s_waitcnt vmcnt(0)" ::: "memory");  // next tile + bias landed
      __builtin_amdgcn_s_barrier();
    }
  }

  // row-sum broadcast via LDS aliased onto dead K/V buffer 0
  __syncthreads();
  float* lrs = (float*)&lKV[0][0];   // per-wave 128B, disjoint
  float tot = (ls[0] + ls[1]) + (ls[2] + ls[3]);
  tot += __shfl_xor(tot, 32);
  lrs[w * 32 + l31] = tot;

  float inv[16];
  #pragma unroll
  for (int r = 0; r < 16; r++)
    inv[r] = 1.0f / lrs[w * 32 + (r & 3) + 8 * (r >> 2) + 4 * hi];

  #pragma unroll
  for (int dt = 0; dt < 2; dt++) {
    #pragma unroll
    for (int r = 0; r < 16; r++) {
      int qrow = q0 + (r & 3) + 8 * (r >> 2) + 4 * hi;
      size_t base = ((size_t)(b * SEQ + qrow)) * DIMC + h * 64 + dt * 32 + l31;
      ao[base] = __bfloat16_as_ushort(__float2bfloat16(O[dt][r] * inv[r]));
    }
  }
}

// ---------------- proj GEMM, 3-buffer counted-vmcnt pipeline ----------------
__global__ void __launch_bounds__(256, 3)
proj_gemm_kernel(const unsigned short* __restrict__ ab,
                 const unsigned short* __restrict__ wT,
                 const float* __restrict__ bias,
                 float* __restrict__ out) {
  __shared__ short lA[3][128 * 32];
  __shared__ short lB[3][128 * 32];
  const int t = threadIdx.x;
  const int lane = t & 63, w = t >> 6;
  const int m0 = blockIdx.x * 128;
  const int n0 = blockIdx.y * 128;
  const int wr = (w >> 1) * 64, wc = (w & 1) * 64;
  const int l15 = lane & 15, lg = lane >> 4;
  const int sr = t >> 2;
  const int sc = t & 3;

  auto STAGE = [&](int k0, int bsel) {
    #pragma unroll
    for (int i = 0; i < 2; i++) {
      int row = i * 64 + sr;
      int cb = (sc ^ ((row >> 1) & 3)) * 8;
      gload_lds16(ab + (size_t)(m0 + row) * DIMC + k0 + cb,
                  (char*)lA + bsel * 8192 + i * 4096 + w * 1024);
      gload_lds16(wT + (size_t)(n0 + row) * DIMC + k0 + cb,
                  (char*)lB + bsel * 8192 + i * 4096 + w * 1024);
    }
  };

  f32x4 acc[4][4] = {};
  const int NT = DIMC / 32;   // 24

  STAGE(0, 0);
  STAGE(32, 1);

  int cur = 0;
  for (int kt = 0; kt < NT; ++kt) {
    if (kt < NT - 1) asm volatile("s_waitcnt vmcnt(4)" ::: "memory");
    else             asm volatile("s_waitcnt vmcnt(0)" ::: "memory");
    __builtin_amdgcn_s_barrier();
    if (kt + 2 < NT) {
      int nb = cur + 2; if (nb >= 3) nb -= 3;
      STAGE((kt + 2) * 32, nb);
    }
    const short* A = &lA[cur][0];
    const short* B = &lB[cur][0];

    bf16x8 af[4], bfr[4];
    #pragma unroll
    for (int mi = 0; mi < 4; mi++) {
      int m = wr + mi * 16 + l15;
      af[mi] = *(const bf16x8*)&A[m * 32 + ((lg ^ ((m >> 1) & 3)) << 3)];
    }
    #pragma unroll
    for (int nj = 0; nj < 4; nj++) {
      int n = wc + nj * 16 + l15;
      bfr[nj] = *(const bf16x8*)&B[n * 32 + ((lg ^ ((n >> 1) & 3)) << 3)];
    }
    __builtin_amdgcn_s_setprio(1);
    #pragma unroll
    for (int mi = 0; mi < 4; mi++)
      #pragma unroll
      for (int nj = 0; nj < 4; nj++)
        acc[mi][nj] = __builtin_amdgcn_mfma_f32_16x16x32_bf16(af[mi], bfr[nj], acc[mi][nj], 0, 0, 0);
    __builtin_amdgcn_s_setprio(0);

    cur = (cur == 2) ? 0 : cur + 1;
  }

  #pragma unroll
  for (int mi = 0; mi < 4; mi++) {
    int row0 = m0 + wr + mi * 16 + 4 * lg;
    #pragma unroll
    for (int nj = 0; nj < 4; nj++) {
      int col = n0 + wc + nj * 16 + l15;
      float bv = bias[col];
      #pragma unroll
      for (int r = 0; r < 4; r++)
        out[(size_t)(row0 + r) * DIMC + col] = acc[mi][nj][r] + bv;
    }
  }
}

extern "C" void kernel_launch(void* const* d_in, const int* in_sizes, int n_in,
                              void* d_out, int out_size, void* d_ws, size_t ws_size,
                              hipStream_t stream) {
  const float* x      = (const float*)d_in[0];
  const int*   mask   = (const int*)d_in[1];
  const float* w_qkv  = (const float*)d_in[2];
  const float* w_proj = (const float*)d_in[3];
  const float* b_proj = (const float*)d_in[4];
  float* out = (float*)d_out;

  unsigned short* ws = (unsigned short*)d_ws;
  unsigned short* xb     = ws;                                 // [16384][768]
  unsigned short* wqkvT  = xb    + (size_t)MTOK * DIMC;        // [2304][768]
  unsigned short* wprojT = wqkvT + (size_t)QKVN * DIMC;        // [768][768]
  unsigned short* qbuf   = wprojT + (size_t)DIMC * DIMC;       // [B,H,N,D]
  unsigned short* kbuf   = qbuf  + (size_t)MTOK * DIMC;        // [B,H,pos,D] compacted
  unsigned short* vtbuf  = kbuf  + (size_t)MTOK * DIMC;        // [B,H,D,pos] compacted
  float*          mbias_c = (float*)(vtbuf + (size_t)MTOK * DIMC); // [B][N]
  int*            posmap  = (int*)(mbias_c + MTOK);            // [B*N]
  int*            nvalid  = posmap + MTOK;                     // [8]
  int*            srcidx  = nvalid + 8;                        // [B*N]
  unsigned short* aob    = xb;   // alias: xb dead after kv_gemm

  cvt_bf16_kernel<<<2048, 256, 0, stream>>>(x, xb, MTOK * DIMC / 4);
  maskscan_kernel<<<NB, 256, 0, stream>>>(mask, posmap, srcidx, mbias_c, nvalid);
  transpose_cvt2_kernel<<<dim3(QKVN / 32, DIMC / 32, 2), 256, 0, stream>>>(w_qkv, wqkvT, w_proj, wprojT);
  q_gemm_kernel<<<dim3(128, 6), 256, 0, stream>>>(xb, wqkvT, qbuf);
  kv_gemm_kernel<<<dim3(16, 12, NB), 256, 0, stream>>>(xb, wqkvT, kbuf, vtbuf, srcidx, nvalid);
  zerotail_kernel<<<NB * NHEAD, 256, 0, stream>>>(kbuf, vtbuf, nvalid);
  attn_kernel<<<1536, 256, 0, stream>>>(qbuf, kbuf, vtbuf, mbias_c, nvalid, aob);
  proj_gemm_kernel<<<dim3(128, 6), 256, 0, stream>>>(aob, wprojT, b_proj, out);
}

// Round 15
// 196.462 us; speedup vs baseline: 2.1996x; 1.0179x over previous
//
#include <hip/hip_runtime.h>
#include <hip/hip_bf16.h>
#include <stdint.h>

#define NHEAD 12
#define SEQ   2048
#define NB    8
#define MTOK  (NB*SEQ)        // 16384
#define DIMC  768
#define QKVN  (3*DIMC)        // 2304

typedef __attribute__((ext_vector_type(8))) short bf16x8;
typedef __attribute__((ext_vector_type(4))) float f32x4;
typedef __attribute__((ext_vector_type(16))) float f32x16;
typedef __attribute__((ext_vector_type(4))) unsigned short u16x4;
typedef __attribute__((ext_vector_type(4))) unsigned int u32x4;

typedef const __attribute__((address_space(1))) char glb_char;
typedef __attribute__((address_space(3))) char lds_char;

__device__ __forceinline__ unsigned short f2bf(float f) {
  union { float f; unsigned u; } v; v.f = f;
  return (unsigned short)((v.u + 0x7FFFu + ((v.u >> 16) & 1u)) >> 16);
}

__device__ __forceinline__ void gload_lds16(const void* g, void* l) {
  __builtin_amdgcn_global_load_lds((glb_char*)g, (lds_char*)l, 16, 0, 0);
}

__device__ __forceinline__ unsigned cvtpk_bf16(float lo, float hi) {
  unsigned d;
  asm("v_cvt_pk_bf16_f32 %0, %1, %2" : "=v"(d) : "v"(lo), "v"(hi));
  return d;
}

// q pre-scale folds softmax scale AND log2(e) so attn uses raw exp2 (v_exp_f32)
#define QSCALE 0.18033688011112042f   // 0.125 * log2(e)
#define MASKBIAS -30000.0f

// ---------------- fp32 -> bf16 convert ----------------
__global__ void __launch_bounds__(256, 8)
cvt_bf16_kernel(const float* __restrict__ in,
                unsigned short* __restrict__ out, int n4) {
  int idx = blockIdx.x * blockDim.x + threadIdx.x;
  int stride = gridDim.x * blockDim.x;
  for (int i = idx; i < n4; i += stride) {
    float4 v = ((const float4*)in)[i];
    u16x4 o;
    o.x = f2bf(v.x); o.y = f2bf(v.y); o.z = f2bf(v.z); o.w = f2bf(v.w);
    ((u16x4*)out)[i] = o;
  }
}

// ---------------- mask scan: compacted positions, inverse map, bias ----------------
__global__ void __launch_bounds__(256, 4)
maskscan_kernel(const int* __restrict__ mask, int* __restrict__ posmap,
                int* __restrict__ srcidx, float* __restrict__ mbias_c,
                int* __restrict__ nvalid) {
  __shared__ int sums[256];
  __shared__ int btot;
  const int b = blockIdx.x, t = threadIdx.x;
  const int* m = mask + b * SEQ;
  int loc[8];
  int s = 0;
  #pragma unroll
  for (int i = 0; i < 8; i++) { loc[i] = (m[t * 8 + i] != 0) ? 1 : 0; s += loc[i]; }
  sums[t] = s;
  __syncthreads();
  for (int off = 1; off < 256; off <<= 1) {
    int v = (t >= off) ? sums[t - off] : 0;
    __syncthreads();
    sums[t] += v;
    __syncthreads();
  }
  int excl = sums[t] - s;           // exclusive prefix of this thread's chunk
  if (t == 255) btot = sums[255];
  __syncthreads();
  const int nv = btot;
  #pragma unroll
  for (int i = 0; i < 8; i++) {
    posmap[b * SEQ + t * 8 + i] = loc[i] ? excl : -1;
    if (loc[i]) srcidx[b * SEQ + excl] = t * 8 + i;
    excl += loc[i];
  }
  for (int j = t; j < SEQ; j += 256) {
    mbias_c[b * SEQ + j] = (j < nv) ? 0.0f : MASKBIAS;
    if (j >= nv) srcidx[b * SEQ + j] = 0;
  }
  if (t == 0) nvalid[b] = nv;
}

// ---------------- fp32 [R][C] -> bf16 [C][R] transpose, both weights fused ----------------
// z=0: w_qkv (R=DIMC, C=QKVN) -> wqkvT ; z=1: w_proj (R=DIMC, C=DIMC) -> wprojT
__global__ void __launch_bounds__(256, 8)
transpose_cvt2_kernel(const float* __restrict__ in0, unsigned short* __restrict__ out0,
                      const float* __restrict__ in1, unsigned short* __restrict__ out1) {
  __shared__ float tile[32][33];
  const int z = blockIdx.z;
  const float* in = z ? in1 : in0;
  unsigned short* out = z ? out1 : out0;
  const int C = z ? DIMC : QKVN;
  const int R = DIMC;
  int c0 = blockIdx.x * 32, r0 = blockIdx.y * 32;
  if (c0 >= C) return;
  int tx = threadIdx.x & 31, ty = threadIdx.x >> 5;  // 256 thr: ty 0..7
  #pragma unroll
  for (int i = 0; i < 32; i += 8)
    tile[ty + i][tx] = in[(size_t)(r0 + ty + i) * C + c0 + tx];
  __syncthreads();
  #pragma unroll
  for (int i = 0; i < 32; i += 8)
    out[(size_t)(c0 + ty + i) * R + r0 + tx] = f2bf(tile[tx][ty + i]);
}

// ---------------- fused Q + KV GEMM, 3-buf counted-vmcnt pipeline ----------------
// z in [0,8): KV GEMM for batch z over COMPACTED rows (gather-in-STAGE);
//             pad rows (pos >= nvalid) get finite garbage — killed in attn by
//             the -30000 bias (exp2 -> exactly 0), so no zeroing pass needed.
// z in [8,12): Q GEMM part (z-8): covers q-blocks [(z-8)*192, (z-8)*192+192).
__global__ void __launch_bounds__(256, 3)
qkv_gemm_kernel(const unsigned short* __restrict__ xb,
                const unsigned short* __restrict__ wT,
                unsigned short* __restrict__ qo,
                unsigned short* __restrict__ ko,
                unsigned short* __restrict__ vto,
                const int* __restrict__ srcidx,
                const int* __restrict__ nvalid) {
  __shared__ short lA[3][128 * 32];
  __shared__ short lB[3][128 * 32];
  const int t = threadIdx.x;
  const int lane = t & 63, w = t >> 6;
  const int wr = (w >> 1) * 64, wc = (w & 1) * 64;
  const int l15 = lane & 15, lg = lane >> 4;
  const int sr = t >> 2;
  const int sc = t & 3;
  const int z = blockIdx.z;
  const int NT = DIMC / 32;   // 24

  if (z < NB) {
    // ================= KV branch =================
    const int b = z;
    const int m0 = blockIdx.x * 128;
    if (m0 >= ((nvalid[b] + 127) & ~127)) return;
    const int n0 = blockIdx.y * 128;

    const int srow0 = srcidx[b * SEQ + m0 + sr];
    const int srow1 = srcidx[b * SEQ + m0 + 64 + sr];
    const unsigned short* xbb = xb + (size_t)b * SEQ * DIMC;
    const unsigned short* wTkv = wT + (size_t)DIMC * DIMC;  // rows [768, 2304)

    auto STAGE = [&](int k0, int bsel) {
      int cb = (sc ^ ((sr >> 1) & 3)) * 8;
      gload_lds16(xbb + (size_t)srow0 * DIMC + k0 + cb,
                  (char*)lA + bsel * 8192 + w * 1024);
      gload_lds16(xbb + (size_t)srow1 * DIMC + k0 + cb,
                  (char*)lA + bsel * 8192 + 4096 + w * 1024);
      #pragma unroll
      for (int i = 0; i < 2; i++) {
        int row = i * 64 + sr;
        int cb2 = (sc ^ ((row >> 1) & 3)) * 8;
        gload_lds16(wTkv + (size_t)(n0 + row) * DIMC + k0 + cb2,
                    (char*)lB + bsel * 8192 + i * 4096 + w * 1024);
      }
    };

    f32x4 acc[4][4] = {};
    STAGE(0, 0);
    STAGE(32, 1);
    int cur = 0;
    for (int kt = 0; kt < NT; ++kt) {
      if (kt < NT - 1) asm volatile("s_waitcnt vmcnt(4)" ::: "memory");
      else             asm volatile("s_waitcnt vmcnt(0)" ::: "memory");
      __builtin_amdgcn_s_barrier();
      if (kt + 2 < NT) {
        int nb = cur + 2; if (nb >= 3) nb -= 3;
        STAGE((kt + 2) * 32, nb);
      }
      const short* A = &lA[cur][0];
      const short* B = &lB[cur][0];

      bf16x8 af[4], bfr[4];
      #pragma unroll
      for (int mi = 0; mi < 4; mi++) {
        int m = wr + mi * 16 + l15;
        af[mi] = *(const bf16x8*)&A[m * 32 + ((lg ^ ((m >> 1) & 3)) << 3)];
      }
      #pragma unroll
      for (int nj = 0; nj < 4; nj++) {
        int n = wc + nj * 16 + l15;
        bfr[nj] = *(const bf16x8*)&B[n * 32 + ((lg ^ ((n >> 1) & 3)) << 3)];
      }
      __builtin_amdgcn_s_setprio(1);
      #pragma unroll
      for (int mi = 0; mi < 4; mi++)
        #pragma unroll
        for (int nj = 0; nj < 4; nj++)
          acc[mi][nj] = __builtin_amdgcn_mfma_f32_16x16x32_bf16(af[mi], bfr[nj], acc[mi][nj], 0, 0, 0);
      __builtin_amdgcn_s_setprio(0);

      cur = (cur == 2) ? 0 : cur + 1;
    }

    #pragma unroll
    for (int mi = 0; mi < 4; mi++) {
      int pos0 = m0 + wr + mi * 16 + 4 * lg;
      #pragma unroll
      for (int nj = 0; nj < 4; nj++) {
        int col = n0 + wc + nj * 16 + l15;     // [0,1536)
        int ch = (col >= DIMC) ? col - DIMC : col;
        int hh = ch >> 6, dd = ch & 63;
        size_t hb = (size_t)(b * NHEAD + hh);
        if (col < DIMC) {
          size_t base = (hb * SEQ + pos0) * 64 + dd;
          #pragma unroll
          for (int r = 0; r < 4; r++)
            ko[base + (size_t)r * 64] = f2bf(acc[mi][nj][r]);
        } else {
          size_t base = (hb * 64 + dd) * SEQ + pos0;
          u16x4 pk;
          pk.x = f2bf(acc[mi][nj][0]); pk.y = f2bf(acc[mi][nj][1]);
          pk.z = f2bf(acc[mi][nj][2]); pk.w = f2bf(acc[mi][nj][3]);
          *(u16x4*)(vto + base) = pk;
        }
      }
    }
  } else {
    // ================= Q branch =================
    const int id = (z - NB) * 192 + blockIdx.y * 16 + blockIdx.x;  // [0,768)
    const int m0 = (id / 6) * 128;
    const int n0 = (id % 6) * 128;

    auto STAGE = [&](int k0, int bsel) {
      #pragma unroll
      for (int i = 0; i < 2; i++) {
        int row = i * 64 + sr;
        int cb = (sc ^ ((row >> 1) & 3)) * 8;
        gload_lds16(xb + (size_t)(m0 + row) * DIMC + k0 + cb,
                    (char*)lA + bsel * 8192 + i * 4096 + w * 1024);
        gload_lds16(wT + (size_t)(n0 + row) * DIMC + k0 + cb,
                    (char*)lB + bsel * 8192 + i * 4096 + w * 1024);
      }
    };

    f32x4 acc[4][4] = {};
    STAGE(0, 0);
    STAGE(32, 1);
    int cur = 0;
    for (int kt = 0; kt < NT; ++kt) {
      if (kt < NT - 1) asm volatile("s_waitcnt vmcnt(4)" ::: "memory");
      else             asm volatile("s_waitcnt vmcnt(0)" ::: "memory");
      __builtin_amdgcn_s_barrier();
      if (kt + 2 < NT) {
        int nb = cur + 2; if (nb >= 3) nb -= 3;
        STAGE((kt + 2) * 32, nb);
      }
      const short* A = &lA[cur][0];
      const short* B = &lB[cur][0];

      bf16x8 af[4], bfr[4];
      #pragma unroll
      for (int mi = 0; mi < 4; mi++) {
        int m = wr + mi * 16 + l15;
        af[mi] = *(const bf16x8*)&A[m * 32 + ((lg ^ ((m >> 1) & 3)) << 3)];
      }
      #pragma unroll
      for (int nj = 0; nj < 4; nj++) {
        int n = wc + nj * 16 + l15;
        bfr[nj] = *(const bf16x8*)&B[n * 32 + ((lg ^ ((n >> 1) & 3)) << 3)];
      }
      __builtin_amdgcn_s_setprio(1);
      #pragma unroll
      for (int mi = 0; mi < 4; mi++)
        #pragma unroll
        for (int nj = 0; nj < 4; nj++)
          acc[mi][nj] = __builtin_amdgcn_mfma_f32_16x16x32_bf16(af[mi], bfr[nj], acc[mi][nj], 0, 0, 0);
      __builtin_amdgcn_s_setprio(0);

      cur = (cur == 2) ? 0 : cur + 1;
    }

    #pragma unroll
    for (int mi = 0; mi < 4; mi++) {
      int tok0 = m0 + wr + mi * 16 + 4 * lg;
      int bb = tok0 >> 11;
      int nn0 = tok0 & 2047;
      #pragma unroll
      for (int nj = 0; nj < 4; nj++) {
        int col = n0 + wc + nj * 16 + l15;    // < 768
        int hh = col >> 6, dd = col & 63;
        size_t base = (((size_t)(bb * NHEAD + hh)) * SEQ + nn0) * 64 + dd;
        #pragma unroll
        for (int r = 0; r < 4; r++)
          qo[base + (size_t)r * 64] = f2bf(acc[mi][nj][r] * QSCALE);
      }
    }
  }
}

// ---------------- flash attention over COMPACTED keys (r11 verified) ----------------
__global__ void __launch_bounds__(256, 4)
attn_kernel(const unsigned short* __restrict__ qbuf,
            const unsigned short* __restrict__ kbuf,
            const unsigned short* __restrict__ vtbuf,
            const float* __restrict__ mbias_c,
            const int* __restrict__ nvalid,
            unsigned short* __restrict__ ao) {
  __shared__ short lKV[2][8192];   // [buf][ K: 8 chunks*1024B | V: 8 chunks*1024B ]
  __shared__ float lmask[2][64];   // bias double-buffer
  const int t = threadIdx.x, lane = t & 63, w = t >> 6;
  const int l31 = lane & 31, hi = lane >> 5;
  const int bid = blockIdx.x;
  const int qt = bid / 96;
  const int bh = bid - qt * 96;
  const int b = bh / NHEAD, h = bh - b * NHEAD;
  const int q0 = qt * 128 + w * 32;
  const unsigned short* qb = qbuf + (size_t)bh * SEQ * 64;
  const unsigned short* kb = kbuf + (size_t)bh * SEQ * 64;
  const unsigned short* vb = vtbuf + (size_t)bh * 64 * SEQ;
  const float* mb = mbias_c + b * SEQ;
  const int ntiles = (nvalid[b] + 63) >> 6;

  auto STAGE = [&](int tile, int bsel) {
    int kv0 = tile * 64;
    #pragma unroll
    for (int i = 0; i < 2; i++) {
      int c = i * 4 + w;
      gload_lds16(kb + (size_t)(kv0 + lane) * 64 + c * 8,
                  (char*)lKV + bsel * 16384 + c * 1024);
      gload_lds16(vb + (size_t)lane * SEQ + kv0 + c * 8,
                  (char*)lKV + bsel * 16384 + 8192 + c * 1024);
    }
    if (w == 0)
      __builtin_amdgcn_global_load_lds((glb_char*)(mb + tile * 64 + lane),
                                       (lds_char*)&lmask[bsel][0], 4, 0, 0);
  };

  // Q as B-operand: col=q=l31, k=d=dblk*16+hi*8+j
  bf16x8 qf[4];
  #pragma unroll
  for (int dblk = 0; dblk < 4; dblk++)
    qf[dblk] = *(const bf16x8*)(qb + (size_t)(q0 + l31) * 64 + dblk * 16 + hi * 8);

  f32x16 O[2] = {};         // O[dt]: rows=q(reg), cols=d=dt*32+l31
  float ls[4] = {0.f, 0.f, 0.f, 0.f};

  STAGE(0, 0);
  __syncthreads();

  for (int it = 0; it < ntiles; ++it) {
    const int bsel = it & 1;
    const short* Kb = &lKV[bsel][0];
    const short* Vb = &lKV[bsel][4096];
    if (it + 1 < ntiles) STAGE(it + 1, bsel ^ 1);

    #pragma unroll
    for (int kb2 = 0; kb2 < 2; kb2++) {
      // bias -> C-init (kv_local = (r&3)+8*(r>>2)+4*hi), broadcast LDS reads
      f32x4 mb4[4];
      #pragma unroll
      for (int g = 0; g < 4; g++)
        mb4[g] = *(const f32x4*)&lmask[bsel][kb2 * 32 + g * 8 + hi * 4];
      f32x16 S;
      #pragma unroll
      for (int r = 0; r < 16; r++) S[r] = mb4[r >> 2][r & 3];

      // ---- S^T = K . Q^T : contiguous reads, immediate offsets ----
      __builtin_amdgcn_s_setprio(1);
      #pragma unroll
      for (int dblk = 0; dblk < 4; dblk++) {
        bf16x8 kf = *(const bf16x8*)&Kb[(dblk * 2 + hi) * 512 + (kb2 * 32 + l31) * 8];
        S = __builtin_amdgcn_mfma_f32_32x32x16_bf16(kf, qf[dblk], S, 0, 0, 0);
      }
      __builtin_amdgcn_s_setprio(0);

      // ---- p = exp2(s); per-lane row-sums (kv is lane-local) ----
      float p[16];
      #pragma unroll
      for (int r = 0; r < 16; r++) p[r] = __builtin_amdgcn_exp2f(S[r]);
      #pragma unroll
      for (int r = 0; r < 16; r++) ls[r & 3] += p[r];

      // ---- PV A-frags (cvt_pk + permlane32_swap), consumed immediately ----
      #pragma unroll
      for (int half = 0; half < 2; half++) {
        unsigned a0 = cvtpk_bf16(p[half * 8 + 0], p[half * 8 + 1]);
        unsigned a1 = cvtpk_bf16(p[half * 8 + 2], p[half * 8 + 3]);
        unsigned a2 = cvtpk_bf16(p[half * 8 + 4], p[half * 8 + 5]);
        unsigned a3 = cvtpk_bf16(p[half * 8 + 6], p[half * 8 + 7]);
        asm("v_permlane32_swap_b32 %0, %1" : "+v"(a0), "+v"(a2));
        asm("v_permlane32_swap_b32 %0, %1" : "+v"(a1), "+v"(a3));
        union { u32x4 u; bf16x8 f; } cv;
        cv.u = (u32x4){a0, a1, a2, a3};
        // ---- PV: O[dt] += P . V (contiguous V reads) ----
        __builtin_amdgcn_s_setprio(1);
        #pragma unroll
        for (int dt = 0; dt < 2; dt++) {
          bf16x8 vf = *(const bf16x8*)&Vb[(kb2 * 4 + half * 2 + hi) * 512 + (dt * 32 + l31) * 8];
          O[dt] = __builtin_amdgcn_mfma_f32_32x32x16_bf16(cv.f, vf, O[dt], 0, 0, 0);
        }
        __builtin_amdgcn_s_setprio(0);
      }
    }

    if (it + 1 < ntiles) {
      asm volatile("s_waitcnt vmcnt(0)" ::: "memory");  // next tile + bias landed
      __builtin_amdgcn_s_barrier();
    }
  }

  // row-sum broadcast via LDS aliased onto dead K/V buffer 0
  __syncthreads();
  float* lrs = (float*)&lKV[0][0];   // per-wave 128B, disjoint
  float tot = (ls[0] + ls[1]) + (ls[2] + ls[3]);
  tot += __shfl_xor(tot, 32);
  lrs[w * 32 + l31] = tot;

  float inv[16];
  #pragma unroll
  for (int r = 0; r < 16; r++)
    inv[r] = 1.0f / lrs[w * 32 + (r & 3) + 8 * (r >> 2) + 4 * hi];

  #pragma unroll
  for (int dt = 0; dt < 2; dt++) {
    #pragma unroll
    for (int r = 0; r < 16; r++) {
      int qrow = q0 + (r & 3) + 8 * (r >> 2) + 4 * hi;
      size_t base = ((size_t)(b * SEQ + qrow)) * DIMC + h * 64 + dt * 32 + l31;
      ao[base] = __bfloat16_as_ushort(__float2bfloat16(O[dt][r] * inv[r]));
    }
  }
}

// ---------------- proj GEMM, 3-buffer counted-vmcnt pipeline ----------------
__global__ void __launch_bounds__(256, 3)
proj_gemm_kernel(const unsigned short* __restrict__ ab,
                 const unsigned short* __restrict__ wT,
                 const float* __restrict__ bias,
                 float* __restrict__ out) {
  __shared__ short lA[3][128 * 32];
  __shared__ short lB[3][128 * 32];
  const int t = threadIdx.x;
  const int lane = t & 63, w = t >> 6;
  const int m0 = blockIdx.x * 128;
  const int n0 = blockIdx.y * 128;
  const int wr = (w >> 1) * 64, wc = (w & 1) * 64;
  const int l15 = lane & 15, lg = lane >> 4;
  const int sr = t >> 2;
  const int sc = t & 3;

  auto STAGE = [&](int k0, int bsel) {
    #pragma unroll
    for (int i = 0; i < 2; i++) {
      int row = i * 64 + sr;
      int cb = (sc ^ ((row >> 1) & 3)) * 8;
      gload_lds16(ab + (size_t)(m0 + row) * DIMC + k0 + cb,
                  (char*)lA + bsel * 8192 + i * 4096 + w * 1024);
      gload_lds16(wT + (size_t)(n0 + row) * DIMC + k0 + cb,
                  (char*)lB + bsel * 8192 + i * 4096 + w * 1024);
    }
  };

  f32x4 acc[4][4] = {};
  const int NT = DIMC / 32;   // 24

  STAGE(0, 0);
  STAGE(32, 1);

  int cur = 0;
  for (int kt = 0; kt < NT; ++kt) {
    if (kt < NT - 1) asm volatile("s_waitcnt vmcnt(4)" ::: "memory");
    else             asm volatile("s_waitcnt vmcnt(0)" ::: "memory");
    __builtin_amdgcn_s_barrier();
    if (kt + 2 < NT) {
      int nb = cur + 2; if (nb >= 3) nb -= 3;
      STAGE((kt + 2) * 32, nb);
    }
    const short* A = &lA[cur][0];
    const short* B = &lB[cur][0];

    bf16x8 af[4], bfr[4];
    #pragma unroll
    for (int mi = 0; mi < 4; mi++) {
      int m = wr + mi * 16 + l15;
      af[mi] = *(const bf16x8*)&A[m * 32 + ((lg ^ ((m >> 1) & 3)) << 3)];
    }
    #pragma unroll
    for (int nj = 0; nj < 4; nj++) {
      int n = wc + nj * 16 + l15;
      bfr[nj] = *(const bf16x8*)&B[n * 32 + ((lg ^ ((n >> 1) & 3)) << 3)];
    }
    __builtin_amdgcn_s_setprio(1);
    #pragma unroll
    for (int mi = 0; mi < 4; mi++)
      #pragma unroll
      for (int nj = 0; nj < 4; nj++)
        acc[mi][nj] = __builtin_amdgcn_mfma_f32_16x16x32_bf16(af[mi], bfr[nj], acc[mi][nj], 0, 0, 0);
    __builtin_amdgcn_s_setprio(0);

    cur = (cur == 2) ? 0 : cur + 1;
  }

  #pragma unroll
  for (int mi = 0; mi < 4; mi++) {
    int row0 = m0 + wr + mi * 16 + 4 * lg;
    #pragma unroll
    for (int nj = 0; nj < 4; nj++) {
      int col = n0 + wc + nj * 16 + l15;
      float bv = bias[col];
      #pragma unroll
      for (int r = 0; r < 4; r++)
        out[(size_t)(row0 + r) * DIMC + col] = acc[mi][nj][r] + bv;
    }
  }
}

extern "C" void kernel_launch(void* const* d_in, const int* in_sizes, int n_in,
                              void* d_out, int out_size, void* d_ws, size_t ws_size,
                              hipStream_t stream) {
  const float* x      = (const float*)d_in[0];
  const int*   mask   = (const int*)d_in[1];
  const float* w_qkv  = (const float*)d_in[2];
  const float* w_proj = (const float*)d_in[3];
  const float* b_proj = (const float*)d_in[4];
  float* out = (float*)d_out;

  unsigned short* ws = (unsigned short*)d_ws;
  unsigned short* xb     = ws;                                 // [16384][768]
  unsigned short* wqkvT  = xb    + (size_t)MTOK * DIMC;        // [2304][768]
  unsigned short* wprojT = wqkvT + (size_t)QKVN * DIMC;        // [768][768]
  unsigned short* qbuf   = wprojT + (size_t)DIMC * DIMC;       // [B,H,N,D]
  unsigned short* kbuf   = qbuf  + (size_t)MTOK * DIMC;        // [B,H,pos,D] compacted
  unsigned short* vtbuf  = kbuf  + (size_t)MTOK * DIMC;        // [B,H,D,pos] compacted
  float*          mbias_c = (float*)(vtbuf + (size_t)MTOK * DIMC); // [B][N]
  int*            posmap  = (int*)(mbias_c + MTOK);            // [B*N]
  int*            nvalid  = posmap + MTOK;                     // [8]
  int*            srcidx  = nvalid + 8;                        // [B*N]
  unsigned short* aob    = xb;   // alias: xb dead after qkv_gemm

  cvt_bf16_kernel<<<2048, 256, 0, stream>>>(x, xb, MTOK * DIMC / 4);
  maskscan_kernel<<<NB, 256, 0, stream>>>(mask, posmap, srcidx, mbias_c, nvalid);
  transpose_cvt2_kernel<<<dim3(QKVN / 32, DIMC / 32, 2), 256, 0, stream>>>(w_qkv, wqkvT, w_proj, wprojT);
  qkv_gemm_kernel<<<dim3(16, 12, 12), 256, 0, stream>>>(xb, wqkvT, qbuf, kbuf, vtbuf, srcidx, nvalid);
  attn_kernel<<<1536, 256, 0, stream>>>(qbuf, kbuf, vtbuf, mbias_c, nvalid, aob);
  proj_gemm_kernel<<<dim3(128, 6), 256, 0, stream>>>(aob, wprojT, b_proj, out);
}